// Round 5
// baseline (101.589 us; speedup 1.0000x reference)
//
#include <hip/hip_runtime.h>

#define EMB 128
#define KN 16
#define NREL 32

__device__ __forceinline__ float fast_tanh(float x) {
    // exact identity tanh(x) = 1 - 2/(e^{2x}+1); v_exp-based, ~1e-6 abs err.
    const float z = __expf(2.0f * x);
    return 1.0f - __fdividef(2.0f, z + 1.0f);
}

// ---------------- costab: |cos(rela[r], rela[c])| for all 32x32 pairs -------
__global__ __launch_bounds__(256) void pgra_costab_k(const float* __restrict__ rela,
                                                     float* __restrict__ costab) {
    const int pair = blockIdx.x * 4 + (threadIdx.x >> 6);
    const int lane = threadIdx.x & 63;
    const int r = pair >> 5, c = pair & 31;
    const float2 av = ((const float2*)(rela + (size_t)r * EMB))[lane];
    const float2 bv = ((const float2*)(rela + (size_t)c * EMB))[lane];
    float dot = av.x * bv.x + av.y * bv.y;
    float na  = av.x * av.x + av.y * av.y;
    float nb  = bv.x * bv.x + bv.y * bv.y;
    #pragma unroll
    for (int off = 32; off > 0; off >>= 1) {
        dot += __shfl_xor(dot, off);
        na  += __shfl_xor(na,  off);
        nb  += __shfl_xor(nb,  off);
    }
    if (lane == 0)
        costab[pair] = fabsf(dot / (sqrtf(na) * sqrtf(nb) + 1e-8f));
}

// ---------------- Kernel A: gather+aggregate, one (b,j) per wave, x4 loads --
// 1024-thread blocks (16 independent waves, no LDS/barrier) for high resident
// wave count. Each load instr reads TWO rows (32 lanes x float4 per row):
// 8 dwordx4 loads/wave instead of 16 dwordx2 -> half the VMEM instrs and
// address regs, all issued before the softmax so they overlap score compute.
__global__ __launch_bounds__(1024) void pgra_gather4(
    const int* __restrict__ node, const int* __restrict__ relation,
    const int* __restrict__ adj_node, const int* __restrict__ adj_rela,
    const float* __restrict__ node_table, const float* __restrict__ proj_table,
    const float* __restrict__ costab, float* __restrict__ agg, int npair)
{
    const int p = blockIdx.x * 16 + (threadIdx.x >> 6);
    if (p >= npair) return;
    const int lane = threadIdx.x & 63;
    const int hi = lane >> 5;        // which of the two rows this lane serves
    const int l5 = lane & 31;        // float4 slot within the row
    const int b = p >> 4, j = p & 15;

    const int n0  = node[b];
    const int rel = relation[b];
    const int n1  = adj_node[n0 * KN + j];

    const int4* n2p = (const int4*)(adj_node + (size_t)n1 * KN);
    const int4* r1p = (const int4*)(adj_rela + (size_t)n1 * KN);

    // row indices: load q-th instr covers rows k=2q+hi, q=0..7
    int4 nn0 = n2p[0], nn1 = n2p[1], nn2 = n2p[2], nn3 = n2p[3];
    int idx[8];
    idx[0] = hi ? nn0.y : nn0.x;  idx[1] = hi ? nn0.w : nn0.z;
    idx[2] = hi ? nn1.y : nn1.x;  idx[3] = hi ? nn1.w : nn1.z;
    idx[4] = hi ? nn2.y : nn2.x;  idx[5] = hi ? nn2.w : nn2.z;
    idx[6] = hi ? nn3.y : nn3.x;  idx[7] = hi ? nn3.w : nn3.z;

    // issue all 8 gather loads up front
    float4 v[8];
    #pragma unroll
    for (int q = 0; q < 8; ++q)
        v[q] = ((const float4*)(node_table + (size_t)idx[q] * EMB))[l5];

    // scores (wave-uniform) while gathers are in flight
    float sc[KN];
    {
        const int4 r0 = r1p[0], r1v = r1p[1], r2v = r1p[2], r3v = r1p[3];
        sc[0]  = costab[r0.x  * NREL + rel]; sc[1]  = costab[r0.y  * NREL + rel];
        sc[2]  = costab[r0.z  * NREL + rel]; sc[3]  = costab[r0.w  * NREL + rel];
        sc[4]  = costab[r1v.x * NREL + rel]; sc[5]  = costab[r1v.y * NREL + rel];
        sc[6]  = costab[r1v.z * NREL + rel]; sc[7]  = costab[r1v.w * NREL + rel];
        sc[8]  = costab[r2v.x * NREL + rel]; sc[9]  = costab[r2v.y * NREL + rel];
        sc[10] = costab[r2v.z * NREL + rel]; sc[11] = costab[r2v.w * NREL + rel];
        sc[12] = costab[r3v.x * NREL + rel]; sc[13] = costab[r3v.y * NREL + rel];
        sc[14] = costab[r3v.z * NREL + rel]; sc[15] = costab[r3v.w * NREL + rel];
    }
    float m = sc[0];
    #pragma unroll
    for (int k = 1; k < KN; ++k) m = fmaxf(m, sc[k]);
    float sum = 0.f;
    #pragma unroll
    for (int k = 0; k < KN; ++k) { sc[k] = __expf(sc[k] - m); sum += sc[k]; }
    const float inv = __fdividef(1.f, sum);

    // per-lane weights: lane's q-th row is k=2q+hi
    float4 a = make_float4(0.f, 0.f, 0.f, 0.f);
    #pragma unroll
    for (int q = 0; q < 8; ++q) {
        const float w = hi ? sc[2 * q + 1] : sc[2 * q];
        a.x = fmaf(w, v[q].x, a.x);
        a.y = fmaf(w, v[q].y, a.y);
        a.z = fmaf(w, v[q].z, a.z);
        a.w = fmaf(w, v[q].w, a.w);
    }
    // combine the two half-wave row sets
    a.x += __shfl_xor(a.x, 32);
    a.y += __shfl_xor(a.y, 32);
    a.z += __shfl_xor(a.z, 32);
    a.w += __shfl_xor(a.w, 32);

    if (hi == 0) {
        const float4 pj = ((const float4*)(proj_table + (size_t)rel * EMB))[l5];
        float4 o;
        o.x = a.x * inv * pj.x;
        o.y = a.y * inv * pj.y;
        o.z = a.z * inv * pj.z;
        o.w = a.w * inv * pj.w;
        ((float4*)(agg + (size_t)p * EMB))[l5] = o;
    }
}

// ---------------- Kernel B: W0 + hop-2 attention + W1, 2 b per block --------
// (verified round 4) Thread (e, bl) owns ALL 16 j of its b: W0 read once per b.
__global__ __launch_bounds__(256) void pgra_tail2(
    const int* __restrict__ node, const int* __restrict__ relation,
    const int* __restrict__ adj_rela, const float* __restrict__ agg,
    const float* __restrict__ W0, const float* __restrict__ b0,
    const float* __restrict__ W1, const float* __restrict__ b1,
    const float* __restrict__ costab, float* __restrict__ out)
{
    const int blk = blockIdx.x;
    const int tid = threadIdx.x;
    const int e   = tid & 127;
    const int bl  = tid >> 7;
    const int b   = blk * 2 + bl;

    __shared__ float s_agg[2][KN][EMB];
    __shared__ float s_fin[2][EMB];

    {
        const float4* ap = (const float4*)(agg + (size_t)blk * 2 * KN * EMB);
        float4* sp = (float4*)&s_agg[0][0][0];
        #pragma unroll
        for (int q = 0; q < 4; ++q) sp[tid + 256 * q] = ap[tid + 256 * q];
    }
    __syncthreads();

    const int n0  = node[b];
    const int rel = relation[b];

    float acc[KN];
    const float bias = b0[e];
    #pragma unroll
    for (int k = 0; k < KN; ++k) acc[k] = bias;
    for (int ee4 = 0; ee4 < EMB / 4; ++ee4) {
        const float w0v = W0[(4 * ee4 + 0) * EMB + e];
        const float w1v = W0[(4 * ee4 + 1) * EMB + e];
        const float w2v = W0[(4 * ee4 + 2) * EMB + e];
        const float w3v = W0[(4 * ee4 + 3) * EMB + e];
        #pragma unroll
        for (int k = 0; k < KN; ++k) {
            const float4 a = *(const float4*)&s_agg[bl][k][4 * ee4];
            acc[k] = fmaf(a.x, w0v, fmaf(a.y, w1v, fmaf(a.z, w2v, fmaf(a.w, w3v, acc[k]))));
        }
    }

    float sc0[KN];
    float m = -1e30f;
    {
        const int4* r0p = (const int4*)(adj_rela + (size_t)n0 * KN);
        #pragma unroll
        for (int q = 0; q < 4; ++q) {
            const int4 rr = r0p[q];
            sc0[4*q+0] = costab[rr.x * NREL + rel];
            sc0[4*q+1] = costab[rr.y * NREL + rel];
            sc0[4*q+2] = costab[rr.z * NREL + rel];
            sc0[4*q+3] = costab[rr.w * NREL + rel];
        }
    }
    #pragma unroll
    for (int k = 0; k < KN; ++k) m = fmaxf(m, sc0[k]);
    float sum = 0.f;
    #pragma unroll
    for (int k = 0; k < KN; ++k) { sc0[k] = __expf(sc0[k] - m); sum += sc0[k]; }
    const float inv = __fdividef(1.f, sum);
    float fin = 0.f;
    #pragma unroll
    for (int k = 0; k < KN; ++k) fin = fmaf(sc0[k] * inv, fast_tanh(acc[k]), fin);
    s_fin[bl][e] = fin;
    __syncthreads();

    float o = b1[e];
    for (int ee4 = 0; ee4 < EMB / 4; ++ee4) {
        const float w0v = W1[(4 * ee4 + 0) * EMB + e];
        const float w1v = W1[(4 * ee4 + 1) * EMB + e];
        const float w2v = W1[(4 * ee4 + 2) * EMB + e];
        const float w3v = W1[(4 * ee4 + 3) * EMB + e];
        const float4 f = *(const float4*)&s_fin[bl][4 * ee4];
        o = fmaf(f.x, w0v, fmaf(f.y, w1v, fmaf(f.z, w2v, fmaf(f.w, w3v, o))));
    }
    out[(size_t)b * EMB + e] = fast_tanh(o);
}

// ---------------- Fallback fused kernel (round-3 verified correct) ----------
__global__ __launch_bounds__(1024) void pgra_fused(
    const int* __restrict__ node, const int* __restrict__ relation,
    const int* __restrict__ adj_node, const int* __restrict__ adj_rela,
    const float* __restrict__ node_table, const float* __restrict__ proj_table,
    const float* __restrict__ W0, const float* __restrict__ b0,
    const float* __restrict__ W1, const float* __restrict__ b1,
    const float* __restrict__ costab, float* __restrict__ out)
{
    const int b    = blockIdx.x;
    const int tid  = threadIdx.x;
    const int wave = tid >> 6;
    const int lane = tid & 63;

    __shared__ float s_agg[KN][EMB];
    __shared__ float s_part[2][EMB];
    __shared__ float s_fin[EMB];

    const int n0  = node[b];
    const int rel = relation[b];

    {
        const int j  = wave;
        const int n1 = adj_node[n0 * KN + j];
        const int4* n2p = (const int4*)(adj_node + (size_t)n1 * KN);
        const int4* r1p = (const int4*)(adj_rela + (size_t)n1 * KN);
        int   n2[KN];
        float sc[KN];
        #pragma unroll
        for (int q = 0; q < 4; ++q) {
            const int4 nn = n2p[q];
            const int4 rr = r1p[q];
            n2[4*q+0] = nn.x; n2[4*q+1] = nn.y; n2[4*q+2] = nn.z; n2[4*q+3] = nn.w;
            sc[4*q+0] = costab[rr.x * NREL + rel];
            sc[4*q+1] = costab[rr.y * NREL + rel];
            sc[4*q+2] = costab[rr.z * NREL + rel];
            sc[4*q+3] = costab[rr.w * NREL + rel];
        }
        float m = sc[0];
        #pragma unroll
        for (int k = 1; k < KN; ++k) m = fmaxf(m, sc[k]);
        float sum = 0.f;
        #pragma unroll
        for (int k = 0; k < KN; ++k) { sc[k] = __expf(sc[k] - m); sum += sc[k]; }
        const float inv = 1.f / sum;
        float ax = 0.f, ay = 0.f;
        #pragma unroll
        for (int k = 0; k < KN; ++k) {
            const float2 v = ((const float2*)(node_table + (size_t)n2[k] * EMB))[lane];
            ax = fmaf(sc[k], v.x, ax);
            ay = fmaf(sc[k], v.y, ay);
        }
        const float2 pj = ((const float2*)(proj_table + (size_t)rel * EMB))[lane];
        s_agg[j][2*lane]   = ax * inv * pj.x;
        s_agg[j][2*lane+1] = ay * inv * pj.y;
    }
    __syncthreads();

    if (tid < 256) {
        const int e  = tid & 127;
        const int g  = tid >> 7;
        const int jg = g * 8;
        float acc[8];
        const float bias = b0[e];
        #pragma unroll
        for (int q = 0; q < 8; ++q) acc[q] = bias;
        for (int ee4 = 0; ee4 < EMB / 4; ++ee4) {
            const float w0v = W0[(4 * ee4 + 0) * EMB + e];
            const float w1v = W0[(4 * ee4 + 1) * EMB + e];
            const float w2v = W0[(4 * ee4 + 2) * EMB + e];
            const float w3v = W0[(4 * ee4 + 3) * EMB + e];
            #pragma unroll
            for (int q = 0; q < 8; ++q) {
                const float4 a = *(const float4*)&s_agg[jg + q][4 * ee4];
                acc[q] = fmaf(a.x, w0v, fmaf(a.y, w1v, fmaf(a.z, w2v, fmaf(a.w, w3v, acc[q]))));
            }
        }
        float sc0[KN];
        float m = -1e30f;
        #pragma unroll
        for (int k = 0; k < KN; ++k) {
            sc0[k] = costab[adj_rela[n0 * KN + k] * NREL + rel];
            m = fmaxf(m, sc0[k]);
        }
        float sum = 0.f;
        #pragma unroll
        for (int k = 0; k < KN; ++k) { sc0[k] = __expf(sc0[k] - m); sum += sc0[k]; }
        const float inv = 1.f / sum;
        float part = 0.f;
        #pragma unroll
        for (int q = 0; q < 8; ++q)
            part = fmaf(sc0[jg + q] * inv, fast_tanh(acc[q]), part);
        s_part[g][e] = part;
    }
    __syncthreads();

    if (tid < EMB) s_fin[tid] = s_part[0][tid] + s_part[1][tid];
    __syncthreads();

    if (tid < EMB) {
        float acc = b1[tid];
        for (int ee = 0; ee < EMB; ++ee) acc = fmaf(s_fin[ee], W1[ee * EMB + tid], acc);
        out[(size_t)b * EMB + tid] = fast_tanh(acc);
    }
}

extern "C" void kernel_launch(void* const* d_in, const int* in_sizes, int n_in,
                              void* d_out, int out_size, void* d_ws, size_t ws_size,
                              hipStream_t stream) {
    const int*   node       = (const int*)d_in[0];
    const int*   relation   = (const int*)d_in[1];
    const int*   adj_node   = (const int*)d_in[2];
    const int*   adj_rela   = (const int*)d_in[3];
    const float* node_table = (const float*)d_in[4];
    const float* rela_table = (const float*)d_in[5];
    const float* proj_table = (const float*)d_in[6];
    const float* W0         = (const float*)d_in[7];
    const float* b0         = (const float*)d_in[8];
    const float* W1         = (const float*)d_in[9];
    const float* b1         = (const float*)d_in[10];
    float* outp = (float*)d_out;
    const int B = in_sizes[0];

    float* costab = (float*)d_ws;                    // 1024 floats = 4 KB
    float* agg    = (float*)d_ws + 1024;             // B*16*128 floats
    const size_t need = (size_t)(1024 + (size_t)B * KN * EMB) * sizeof(float);

    hipLaunchKernelGGL(pgra_costab_k, dim3(NREL * NREL / 4), dim3(256), 0, stream,
                       rela_table, costab);

    if (ws_size >= need) {
        const int npair = B * KN;      // 32768 waves, one (b,j) each
        hipLaunchKernelGGL(pgra_gather4, dim3((npair + 15) / 16), dim3(1024), 0, stream,
                           node, relation, adj_node, adj_rela,
                           node_table, proj_table, costab, agg, npair);
        hipLaunchKernelGGL(pgra_tail2, dim3(B / 2), dim3(256), 0, stream,
                           node, relation, adj_rela, agg,
                           W0, b0, W1, b1, costab, outp);
    } else {
        hipLaunchKernelGGL(pgra_fused, dim3(B), dim3(1024), 0, stream,
                           node, relation, adj_node, adj_rela,
                           node_table, proj_table, W0, b0, W1, b1, costab, outp);
    }
}

// Round 6
// 91.219 us; speedup vs baseline: 1.1137x; 1.1137x over previous
//
#include <hip/hip_runtime.h>

#define EMB 128
#define KN 16
#define NREL 32

__device__ __forceinline__ float fast_tanh(float x) {
    // exact identity tanh(x) = 1 - 2/(e^{2x}+1); v_exp-based, ~1e-6 abs err.
    const float z = __expf(2.0f * x);
    return 1.0f - __fdividef(2.0f, z + 1.0f);
}

// ---------------- costab: |cos(rela[r], rela[c])| for all 32x32 pairs -------
__global__ __launch_bounds__(256) void pgra_costab_k(const float* __restrict__ rela,
                                                     float* __restrict__ costab) {
    const int pair = blockIdx.x * 4 + (threadIdx.x >> 6);
    const int lane = threadIdx.x & 63;
    const int r = pair >> 5, c = pair & 31;
    const float2 av = ((const float2*)(rela + (size_t)r * EMB))[lane];
    const float2 bv = ((const float2*)(rela + (size_t)c * EMB))[lane];
    float dot = av.x * bv.x + av.y * bv.y;
    float na  = av.x * av.x + av.y * av.y;
    float nb  = bv.x * bv.x + bv.y * bv.y;
    #pragma unroll
    for (int off = 32; off > 0; off >>= 1) {
        dot += __shfl_xor(dot, off);
        na  += __shfl_xor(na,  off);
        nb  += __shfl_xor(nb,  off);
    }
    if (lane == 0)
        costab[pair] = fabsf(dot / (sqrtf(na) * sqrtf(nb) + 1e-8f));
}

// ---------------- Kernel A: gather + attention-aggregate, one wave per (b,j) ---
// EXACT round-2 structure (proven 48 us, 3.0 TB/s): 256-thd blocks, no LDS,
// no barriers, 32768 independent waves.
__global__ __launch_bounds__(256) void pgra_gather(
    const int* __restrict__ node, const int* __restrict__ relation,
    const int* __restrict__ adj_node, const int* __restrict__ adj_rela,
    const float* __restrict__ node_table, const float* __restrict__ proj_table,
    const float* __restrict__ costab, float* __restrict__ agg, int npair)
{
    const int p = blockIdx.x * 4 + (threadIdx.x >> 6);
    if (p >= npair) return;
    const int lane = threadIdx.x & 63;
    const int b = p >> 4, j = p & 15;

    const int n0  = node[b];
    const int rel = relation[b];
    const int n1  = adj_node[n0 * KN + j];

    const int4* n2p = (const int4*)(adj_node + (size_t)n1 * KN);
    const int4* r1p = (const int4*)(adj_rela + (size_t)n1 * KN);
    int   n2[KN];
    float sc[KN];
    #pragma unroll
    for (int q = 0; q < 4; ++q) {
        const int4 nn = n2p[q];
        const int4 rr = r1p[q];
        n2[4*q+0] = nn.x; n2[4*q+1] = nn.y; n2[4*q+2] = nn.z; n2[4*q+3] = nn.w;
        sc[4*q+0] = costab[rr.x * NREL + rel];
        sc[4*q+1] = costab[rr.y * NREL + rel];
        sc[4*q+2] = costab[rr.z * NREL + rel];
        sc[4*q+3] = costab[rr.w * NREL + rel];
    }
    float m = sc[0];
    #pragma unroll
    for (int k = 1; k < KN; ++k) m = fmaxf(m, sc[k]);
    float sum = 0.f;
    #pragma unroll
    for (int k = 0; k < KN; ++k) { sc[k] = __expf(sc[k] - m); sum += sc[k]; }
    const float inv = 1.f / sum;

    float ax = 0.f, ay = 0.f;
    #pragma unroll
    for (int k = 0; k < KN; ++k) {
        const float2 v = ((const float2*)(node_table + (size_t)n2[k] * EMB))[lane];
        ax = fmaf(sc[k], v.x, ax);
        ay = fmaf(sc[k], v.y, ay);
    }
    const float2 pj = ((const float2*)(proj_table + (size_t)rel * EMB))[lane];
    float2 o;
    o.x = ax * inv * pj.x;
    o.y = ay * inv * pj.y;
    ((float2*)(agg + (size_t)p * EMB))[lane] = o;
}

// ---------------- Kernel B: W0 + hop-2 attention + W1, scalar-path agg ------
// Thread (e, bl) owns ALL 16 j of batch element b = 2*blk + bl. The agg-tile
// reads are wave-uniform: readfirstlane forces the base scalar so they compile
// to s_load through the SMEM pipe (parallel to VALU) -- no LDS staging at all.
__global__ __launch_bounds__(256) void pgra_tail3(
    const int* __restrict__ node, const int* __restrict__ relation,
    const int* __restrict__ adj_rela, const float* __restrict__ agg,
    const float* __restrict__ W0, const float* __restrict__ b0,
    const float* __restrict__ W1, const float* __restrict__ b1,
    const float* __restrict__ costab, float* __restrict__ out)
{
    const int blk = blockIdx.x;
    const int tid = threadIdx.x;
    const int e   = tid & 127;
    const int bl  = tid >> 7;             // 0 or 1; uniform per wave
    const int b   = blk * 2 + bl;

    __shared__ float s_fin[2][EMB];

    // wave-uniform scalar handle for this wave's batch element
    const int ub = __builtin_amdgcn_readfirstlane(b);
    const int n0  = node[ub];
    const int rel = relation[ub];
    const float* __restrict__ aggb = agg + (size_t)ub * (KN * EMB);

    // h1[j][e] accumulation for all 16 j of this thread's b.
    // W0 column reads: per-lane coalesced. agg reads: scalar (s_load).
    float acc[KN];
    const float bias = b0[e];
    #pragma unroll
    for (int k = 0; k < KN; ++k) acc[k] = bias;
    for (int ee4 = 0; ee4 < EMB / 4; ++ee4) {
        const float w0v = W0[(4 * ee4 + 0) * EMB + e];
        const float w1v = W0[(4 * ee4 + 1) * EMB + e];
        const float w2v = W0[(4 * ee4 + 2) * EMB + e];
        const float w3v = W0[(4 * ee4 + 3) * EMB + e];
        #pragma unroll
        for (int k = 0; k < KN; ++k) {
            const float4 a = *(const float4*)(aggb + k * EMB + 4 * ee4);
            acc[k] = fmaf(a.x, w0v, fmaf(a.y, w1v, fmaf(a.z, w2v, fmaf(a.w, w3v, acc[k]))));
        }
    }

    // hop-2 attention weights (from r0), folded in-register with fast_tanh
    float sc0[KN];
    float m = -1e30f;
    {
        const int4* r0p = (const int4*)(adj_rela + (size_t)n0 * KN);
        #pragma unroll
        for (int q = 0; q < 4; ++q) {
            const int4 rr = r0p[q];
            sc0[4*q+0] = costab[rr.x * NREL + rel];
            sc0[4*q+1] = costab[rr.y * NREL + rel];
            sc0[4*q+2] = costab[rr.z * NREL + rel];
            sc0[4*q+3] = costab[rr.w * NREL + rel];
        }
    }
    #pragma unroll
    for (int k = 0; k < KN; ++k) m = fmaxf(m, sc0[k]);
    float sum = 0.f;
    #pragma unroll
    for (int k = 0; k < KN; ++k) { sc0[k] = __expf(sc0[k] - m); sum += sc0[k]; }
    const float inv = __fdividef(1.f, sum);
    float fin = 0.f;
    #pragma unroll
    for (int k = 0; k < KN; ++k) fin = fmaf(sc0[k] * inv, fast_tanh(acc[k]), fin);
    s_fin[bl][e] = fin;
    __syncthreads();

    // out = tanh(fin @ W1 + b1); s_fin reads are tiny LDS broadcasts
    float o = b1[e];
    for (int ee4 = 0; ee4 < EMB / 4; ++ee4) {
        const float w0v = W1[(4 * ee4 + 0) * EMB + e];
        const float w1v = W1[(4 * ee4 + 1) * EMB + e];
        const float w2v = W1[(4 * ee4 + 2) * EMB + e];
        const float w3v = W1[(4 * ee4 + 3) * EMB + e];
        const float4 f = *(const float4*)&s_fin[bl][4 * ee4];
        o = fmaf(f.x, w0v, fmaf(f.y, w1v, fmaf(f.z, w2v, fmaf(f.w, w3v, o))));
    }
    out[(size_t)b * EMB + e] = fast_tanh(o);
}

// ---------------- Fallback fused kernel (round-3/4 verified correct) --------
__global__ __launch_bounds__(1024) void pgra_fused(
    const int* __restrict__ node, const int* __restrict__ relation,
    const int* __restrict__ adj_node, const int* __restrict__ adj_rela,
    const float* __restrict__ node_table, const float* __restrict__ proj_table,
    const float* __restrict__ W0, const float* __restrict__ b0,
    const float* __restrict__ W1, const float* __restrict__ b1,
    const float* __restrict__ costab, float* __restrict__ out)
{
    const int b    = blockIdx.x;
    const int tid  = threadIdx.x;
    const int wave = tid >> 6;
    const int lane = tid & 63;

    __shared__ float s_agg[KN][EMB];
    __shared__ float s_part[2][EMB];
    __shared__ float s_fin[EMB];

    const int n0  = node[b];
    const int rel = relation[b];

    {
        const int j  = wave;
        const int n1 = adj_node[n0 * KN + j];
        const int4* n2p = (const int4*)(adj_node + (size_t)n1 * KN);
        const int4* r1p = (const int4*)(adj_rela + (size_t)n1 * KN);
        int   n2[KN];
        float sc[KN];
        #pragma unroll
        for (int q = 0; q < 4; ++q) {
            const int4 nn = n2p[q];
            const int4 rr = r1p[q];
            n2[4*q+0] = nn.x; n2[4*q+1] = nn.y; n2[4*q+2] = nn.z; n2[4*q+3] = nn.w;
            sc[4*q+0] = costab[rr.x * NREL + rel];
            sc[4*q+1] = costab[rr.y * NREL + rel];
            sc[4*q+2] = costab[rr.z * NREL + rel];
            sc[4*q+3] = costab[rr.w * NREL + rel];
        }
        float m = sc[0];
        #pragma unroll
        for (int k = 1; k < KN; ++k) m = fmaxf(m, sc[k]);
        float sum = 0.f;
        #pragma unroll
        for (int k = 0; k < KN; ++k) { sc[k] = __expf(sc[k] - m); sum += sc[k]; }
        const float inv = 1.f / sum;
        float ax = 0.f, ay = 0.f;
        #pragma unroll
        for (int k = 0; k < KN; ++k) {
            const float2 v = ((const float2*)(node_table + (size_t)n2[k] * EMB))[lane];
            ax = fmaf(sc[k], v.x, ax);
            ay = fmaf(sc[k], v.y, ay);
        }
        const float2 pj = ((const float2*)(proj_table + (size_t)rel * EMB))[lane];
        s_agg[j][2*lane]   = ax * inv * pj.x;
        s_agg[j][2*lane+1] = ay * inv * pj.y;
    }
    __syncthreads();

    if (tid < 256) {
        const int e  = tid & 127;
        const int g  = tid >> 7;
        const int jg = g * 8;
        float acc[8];
        const float bias = b0[e];
        #pragma unroll
        for (int q = 0; q < 8; ++q) acc[q] = bias;
        for (int ee4 = 0; ee4 < EMB / 4; ++ee4) {
            const float w0v = W0[(4 * ee4 + 0) * EMB + e];
            const float w1v = W0[(4 * ee4 + 1) * EMB + e];
            const float w2v = W0[(4 * ee4 + 2) * EMB + e];
            const float w3v = W0[(4 * ee4 + 3) * EMB + e];
            #pragma unroll
            for (int q = 0; q < 8; ++q) {
                const float4 a = *(const float4*)&s_agg[jg + q][4 * ee4];
                acc[q] = fmaf(a.x, w0v, fmaf(a.y, w1v, fmaf(a.z, w2v, fmaf(a.w, w3v, acc[q]))));
            }
        }
        float sc0[KN];
        float m = -1e30f;
        #pragma unroll
        for (int k = 0; k < KN; ++k) {
            sc0[k] = costab[adj_rela[n0 * KN + k] * NREL + rel];
            m = fmaxf(m, sc0[k]);
        }
        float sum = 0.f;
        #pragma unroll
        for (int k = 0; k < KN; ++k) { sc0[k] = __expf(sc0[k] - m); sum += sc0[k]; }
        const float inv = 1.f / sum;
        float part = 0.f;
        #pragma unroll
        for (int q = 0; q < 8; ++q)
            part = fmaf(sc0[jg + q] * inv, fast_tanh(acc[q]), part);
        s_part[g][e] = part;
    }
    __syncthreads();

    if (tid < EMB) s_fin[tid] = s_part[0][tid] + s_part[1][tid];
    __syncthreads();

    if (tid < EMB) {
        float acc = b1[tid];
        for (int ee = 0; ee < EMB; ++ee) acc = fmaf(s_fin[ee], W1[ee * EMB + tid], acc);
        out[(size_t)b * EMB + tid] = fast_tanh(acc);
    }
}

extern "C" void kernel_launch(void* const* d_in, const int* in_sizes, int n_in,
                              void* d_out, int out_size, void* d_ws, size_t ws_size,
                              hipStream_t stream) {
    const int*   node       = (const int*)d_in[0];
    const int*   relation   = (const int*)d_in[1];
    const int*   adj_node   = (const int*)d_in[2];
    const int*   adj_rela   = (const int*)d_in[3];
    const float* node_table = (const float*)d_in[4];
    const float* rela_table = (const float*)d_in[5];
    const float* proj_table = (const float*)d_in[6];
    const float* W0         = (const float*)d_in[7];
    const float* b0         = (const float*)d_in[8];
    const float* W1         = (const float*)d_in[9];
    const float* b1         = (const float*)d_in[10];
    float* outp = (float*)d_out;
    const int B = in_sizes[0];

    float* costab = (float*)d_ws;                    // 1024 floats = 4 KB
    float* agg    = (float*)d_ws + 1024;             // B*16*128 floats
    const size_t need = (size_t)(1024 + (size_t)B * KN * EMB) * sizeof(float);

    hipLaunchKernelGGL(pgra_costab_k, dim3(NREL * NREL / 4), dim3(256), 0, stream,
                       rela_table, costab);

    if (ws_size >= need) {
        const int npair = B * KN;      // 32768 waves, one (b,j) each
        hipLaunchKernelGGL(pgra_gather, dim3((npair + 3) / 4), dim3(256), 0, stream,
                           node, relation, adj_node, adj_rela,
                           node_table, proj_table, costab, agg, npair);
        hipLaunchKernelGGL(pgra_tail3, dim3(B / 2), dim3(256), 0, stream,
                           node, relation, adj_rela, agg,
                           W0, b0, W1, b1, costab, outp);
    } else {
        hipLaunchKernelGGL(pgra_fused, dim3(B), dim3(1024), 0, stream,
                           node, relation, adj_node, adj_rela,
                           node_table, proj_table, W0, b0, W1, b1, costab, outp);
    }
}

// Round 7
// 81.130 us; speedup vs baseline: 1.2522x; 1.1244x over previous
//
#include <hip/hip_runtime.h>

#define EMB 128
#define KN 16
#define NREL 32

__device__ __forceinline__ float fast_tanh(float x) {
    // exact identity tanh(x) = 1 - 2/(e^{2x}+1); v_exp-based, ~1e-6 abs err.
    const float z = __expf(2.0f * x);
    return 1.0f - __fdividef(2.0f, z + 1.0f);
}

// ---------------- costab: |cos(rela[r], rela[c])| for all 32x32 pairs -------
__global__ __launch_bounds__(256) void pgra_costab_k(const float* __restrict__ rela,
                                                     float* __restrict__ costab) {
    const int pair = blockIdx.x * 4 + (threadIdx.x >> 6);
    const int lane = threadIdx.x & 63;
    const int r = pair >> 5, c = pair & 31;
    const float2 av = ((const float2*)(rela + (size_t)r * EMB))[lane];
    const float2 bv = ((const float2*)(rela + (size_t)c * EMB))[lane];
    float dot = av.x * bv.x + av.y * bv.y;
    float na  = av.x * av.x + av.y * av.y;
    float nb  = bv.x * bv.x + bv.y * bv.y;
    #pragma unroll
    for (int off = 32; off > 0; off >>= 1) {
        dot += __shfl_xor(dot, off);
        na  += __shfl_xor(na,  off);
        nb  += __shfl_xor(nb,  off);
    }
    if (lane == 0)
        costab[pair] = fabsf(dot / (sqrtf(na) * sqrtf(nb) + 1e-8f));
}

// ---------------- Kernel A: gather + attention-aggregate, one wave per (b,j) ---
// EXACT round-2/6 structure (proven 48 us, 3.0 TB/s fetch): 256-thd blocks,
// no LDS, no barriers, 32768 independent waves. Do not touch.
__global__ __launch_bounds__(256) void pgra_gather(
    const int* __restrict__ node, const int* __restrict__ relation,
    const int* __restrict__ adj_node, const int* __restrict__ adj_rela,
    const float* __restrict__ node_table, const float* __restrict__ proj_table,
    const float* __restrict__ costab, float* __restrict__ agg, int npair)
{
    const int p = blockIdx.x * 4 + (threadIdx.x >> 6);
    if (p >= npair) return;
    const int lane = threadIdx.x & 63;
    const int b = p >> 4, j = p & 15;

    const int n0  = node[b];
    const int rel = relation[b];
    const int n1  = adj_node[n0 * KN + j];

    const int4* n2p = (const int4*)(adj_node + (size_t)n1 * KN);
    const int4* r1p = (const int4*)(adj_rela + (size_t)n1 * KN);
    int   n2[KN];
    float sc[KN];
    #pragma unroll
    for (int q = 0; q < 4; ++q) {
        const int4 nn = n2p[q];
        const int4 rr = r1p[q];
        n2[4*q+0] = nn.x; n2[4*q+1] = nn.y; n2[4*q+2] = nn.z; n2[4*q+3] = nn.w;
        sc[4*q+0] = costab[rr.x * NREL + rel];
        sc[4*q+1] = costab[rr.y * NREL + rel];
        sc[4*q+2] = costab[rr.z * NREL + rel];
        sc[4*q+3] = costab[rr.w * NREL + rel];
    }
    float m = sc[0];
    #pragma unroll
    for (int k = 1; k < KN; ++k) m = fmaxf(m, sc[k]);
    float sum = 0.f;
    #pragma unroll
    for (int k = 0; k < KN; ++k) { sc[k] = __expf(sc[k] - m); sum += sc[k]; }
    const float inv = 1.f / sum;

    float ax = 0.f, ay = 0.f;
    #pragma unroll
    for (int k = 0; k < KN; ++k) {
        const float2 v = ((const float2*)(node_table + (size_t)n2[k] * EMB))[lane];
        ax = fmaf(sc[k], v.x, ax);
        ay = fmaf(sc[k], v.y, ay);
    }
    const float2 pj = ((const float2*)(proj_table + (size_t)rel * EMB))[lane];
    float2 o;
    o.x = ax * inv * pj.x;
    o.y = ay * inv * pj.y;
    ((float2*)(agg + (size_t)p * EMB))[lane] = o;
}

// ---------------- Kernel B: tail4 — one wave per b, 2 output cols per lane ---
// Lane owns e = {lane, lane+64}: each broadcast ds_read_b128 of an agg quad
// feeds 8 fma (vs 4 in the old layout) -> half the LDS wave-instructions,
// same W0 L2 traffic (64 KB/b). acc[16]x2 statically indexed, ~80 VGPR.
__global__ __launch_bounds__(256) void pgra_tail4(
    const int* __restrict__ node, const int* __restrict__ relation,
    const int* __restrict__ adj_rela, const float* __restrict__ agg,
    const float* __restrict__ W0, const float* __restrict__ b0,
    const float* __restrict__ W1, const float* __restrict__ b1,
    const float* __restrict__ costab, float* __restrict__ out)
{
    const int blk  = blockIdx.x;          // B/4 blocks
    const int tid  = threadIdx.x;
    const int wave = tid >> 6;            // 0..3 -> which b of this block
    const int lane = tid & 63;
    const int b    = blk * 4 + wave;

    __shared__ float s_agg[4][KN][EMB];   // 32 KB
    __shared__ float s_fin[4][EMB];       //  2 KB

    // stage 4 agg tiles (8192 floats = 2048 float4), fully coalesced
    {
        const float4* ap = (const float4*)(agg + (size_t)blk * 4 * KN * EMB);
        float4* sp = (float4*)&s_agg[0][0][0];
        #pragma unroll
        for (int q = 0; q < 8; ++q) sp[tid + 256 * q] = ap[tid + 256 * q];
    }
    __syncthreads();

    const int n0  = node[b];              // wave-uniform
    const int rel = relation[b];

    // h1 accumulation: acc0[k] -> e=lane, acc1[k] -> e=lane+64
    float acc0[KN], acc1[KN];
    const float bias0 = b0[lane];
    const float bias1 = b0[lane + 64];
    #pragma unroll
    for (int k = 0; k < KN; ++k) { acc0[k] = bias0; acc1[k] = bias1; }

    for (int ee4 = 0; ee4 < EMB / 4; ++ee4) {
        const int row = 4 * ee4;
        float w0a[4], w0b[4];
        #pragma unroll
        for (int r = 0; r < 4; ++r) {
            w0a[r] = W0[(row + r) * EMB + lane];
            w0b[r] = W0[(row + r) * EMB + lane + 64];
        }
        #pragma unroll
        for (int k = 0; k < KN; ++k) {
            const float4 a = *(const float4*)&s_agg[wave][k][row];   // broadcast
            acc0[k] = fmaf(a.x, w0a[0], fmaf(a.y, w0a[1], fmaf(a.z, w0a[2], fmaf(a.w, w0a[3], acc0[k]))));
            acc1[k] = fmaf(a.x, w0b[0], fmaf(a.y, w0b[1], fmaf(a.z, w0b[2], fmaf(a.w, w0b[3], acc1[k]))));
        }
    }

    // hop-2 attention weights (from r0), folded in-register with fast_tanh
    float sc0[KN];
    float m = -1e30f;
    {
        const int4* r0p = (const int4*)(adj_rela + (size_t)n0 * KN);
        #pragma unroll
        for (int q = 0; q < 4; ++q) {
            const int4 rr = r0p[q];
            sc0[4*q+0] = costab[rr.x * NREL + rel];
            sc0[4*q+1] = costab[rr.y * NREL + rel];
            sc0[4*q+2] = costab[rr.z * NREL + rel];
            sc0[4*q+3] = costab[rr.w * NREL + rel];
        }
    }
    #pragma unroll
    for (int k = 0; k < KN; ++k) m = fmaxf(m, sc0[k]);
    float sum = 0.f;
    #pragma unroll
    for (int k = 0; k < KN; ++k) { sc0[k] = __expf(sc0[k] - m); sum += sc0[k]; }
    const float inv = __fdividef(1.f, sum);
    float fin0 = 0.f, fin1 = 0.f;
    #pragma unroll
    for (int k = 0; k < KN; ++k) {
        const float w = sc0[k] * inv;
        fin0 = fmaf(w, fast_tanh(acc0[k]), fin0);
        fin1 = fmaf(w, fast_tanh(acc1[k]), fin1);
    }
    s_fin[wave][lane]      = fin0;
    s_fin[wave][lane + 64] = fin1;
    __syncthreads();

    // out = tanh(fin @ W1 + b1), same 2-col-per-lane layout
    float o0 = b1[lane], o1 = b1[lane + 64];
    for (int ee4 = 0; ee4 < EMB / 4; ++ee4) {
        const int row = 4 * ee4;
        const float4 f = *(const float4*)&s_fin[wave][row];          // broadcast
        float w1a[4], w1b[4];
        #pragma unroll
        for (int r = 0; r < 4; ++r) {
            w1a[r] = W1[(row + r) * EMB + lane];
            w1b[r] = W1[(row + r) * EMB + lane + 64];
        }
        o0 = fmaf(f.x, w1a[0], fmaf(f.y, w1a[1], fmaf(f.z, w1a[2], fmaf(f.w, w1a[3], o0))));
        o1 = fmaf(f.x, w1b[0], fmaf(f.y, w1b[1], fmaf(f.z, w1b[2], fmaf(f.w, w1b[3], o1))));
    }
    out[(size_t)b * EMB + lane]      = fast_tanh(o0);
    out[(size_t)b * EMB + lane + 64] = fast_tanh(o1);
}

// ---------------- Fallback fused kernel (round-3/4 verified correct) --------
__global__ __launch_bounds__(1024) void pgra_fused(
    const int* __restrict__ node, const int* __restrict__ relation,
    const int* __restrict__ adj_node, const int* __restrict__ adj_rela,
    const float* __restrict__ node_table, const float* __restrict__ proj_table,
    const float* __restrict__ W0, const float* __restrict__ b0,
    const float* __restrict__ W1, const float* __restrict__ b1,
    const float* __restrict__ costab, float* __restrict__ out)
{
    const int b    = blockIdx.x;
    const int tid  = threadIdx.x;
    const int wave = tid >> 6;
    const int lane = tid & 63;

    __shared__ float s_agg[KN][EMB];
    __shared__ float s_part[2][EMB];
    __shared__ float s_fin[EMB];

    const int n0  = node[b];
    const int rel = relation[b];

    {
        const int j  = wave;
        const int n1 = adj_node[n0 * KN + j];
        const int4* n2p = (const int4*)(adj_node + (size_t)n1 * KN);
        const int4* r1p = (const int4*)(adj_rela + (size_t)n1 * KN);
        int   n2[KN];
        float sc[KN];
        #pragma unroll
        for (int q = 0; q < 4; ++q) {
            const int4 nn = n2p[q];
            const int4 rr = r1p[q];
            n2[4*q+0] = nn.x; n2[4*q+1] = nn.y; n2[4*q+2] = nn.z; n2[4*q+3] = nn.w;
            sc[4*q+0] = costab[rr.x * NREL + rel];
            sc[4*q+1] = costab[rr.y * NREL + rel];
            sc[4*q+2] = costab[rr.z * NREL + rel];
            sc[4*q+3] = costab[rr.w * NREL + rel];
        }
        float m = sc[0];
        #pragma unroll
        for (int k = 1; k < KN; ++k) m = fmaxf(m, sc[k]);
        float sum = 0.f;
        #pragma unroll
        for (int k = 0; k < KN; ++k) { sc[k] = __expf(sc[k] - m); sum += sc[k]; }
        const float inv = 1.f / sum;
        float ax = 0.f, ay = 0.f;
        #pragma unroll
        for (int k = 0; k < KN; ++k) {
            const float2 v = ((const float2*)(node_table + (size_t)n2[k] * EMB))[lane];
            ax = fmaf(sc[k], v.x, ax);
            ay = fmaf(sc[k], v.y, ay);
        }
        const float2 pj = ((const float2*)(proj_table + (size_t)rel * EMB))[lane];
        s_agg[j][2*lane]   = ax * inv * pj.x;
        s_agg[j][2*lane+1] = ay * inv * pj.y;
    }
    __syncthreads();

    if (tid < 256) {
        const int e  = tid & 127;
        const int g  = tid >> 7;
        const int jg = g * 8;
        float acc[8];
        const float bias = b0[e];
        #pragma unroll
        for (int q = 0; q < 8; ++q) acc[q] = bias;
        for (int ee4 = 0; ee4 < EMB / 4; ++ee4) {
            const float w0v = W0[(4 * ee4 + 0) * EMB + e];
            const float w1v = W0[(4 * ee4 + 1) * EMB + e];
            const float w2v = W0[(4 * ee4 + 2) * EMB + e];
            const float w3v = W0[(4 * ee4 + 3) * EMB + e];
            #pragma unroll
            for (int q = 0; q < 8; ++q) {
                const float4 a = *(const float4*)&s_agg[jg + q][4 * ee4];
                acc[q] = fmaf(a.x, w0v, fmaf(a.y, w1v, fmaf(a.z, w2v, fmaf(a.w, w3v, acc[q]))));
            }
        }
        float sc0[KN];
        float m = -1e30f;
        #pragma unroll
        for (int k = 0; k < KN; ++k) {
            sc0[k] = costab[adj_rela[n0 * KN + k] * NREL + rel];
            m = fmaxf(m, sc0[k]);
        }
        float sum = 0.f;
        #pragma unroll
        for (int k = 0; k < KN; ++k) { sc0[k] = __expf(sc0[k] - m); sum += sc0[k]; }
        const float inv = 1.f / sum;
        float part = 0.f;
        #pragma unroll
        for (int q = 0; q < 8; ++q)
            part = fmaf(sc0[jg + q] * inv, fast_tanh(acc[q]), part);
        s_part[g][e] = part;
    }
    __syncthreads();

    if (tid < EMB) s_fin[tid] = s_part[0][tid] + s_part[1][tid];
    __syncthreads();

    if (tid < EMB) {
        float acc = b1[tid];
        for (int ee = 0; ee < EMB; ++ee) acc = fmaf(s_fin[ee], W1[ee * EMB + tid], acc);
        out[(size_t)b * EMB + tid] = fast_tanh(acc);
    }
}

extern "C" void kernel_launch(void* const* d_in, const int* in_sizes, int n_in,
                              void* d_out, int out_size, void* d_ws, size_t ws_size,
                              hipStream_t stream) {
    const int*   node       = (const int*)d_in[0];
    const int*   relation   = (const int*)d_in[1];
    const int*   adj_node   = (const int*)d_in[2];
    const int*   adj_rela   = (const int*)d_in[3];
    const float* node_table = (const float*)d_in[4];
    const float* rela_table = (const float*)d_in[5];
    const float* proj_table = (const float*)d_in[6];
    const float* W0         = (const float*)d_in[7];
    const float* b0         = (const float*)d_in[8];
    const float* W1         = (const float*)d_in[9];
    const float* b1         = (const float*)d_in[10];
    float* outp = (float*)d_out;
    const int B = in_sizes[0];

    float* costab = (float*)d_ws;                    // 1024 floats = 4 KB
    float* agg    = (float*)d_ws + 1024;             // B*16*128 floats
    const size_t need = (size_t)(1024 + (size_t)B * KN * EMB) * sizeof(float);

    hipLaunchKernelGGL(pgra_costab_k, dim3(NREL * NREL / 4), dim3(256), 0, stream,
                       rela_table, costab);

    if (ws_size >= need && (B % 4) == 0) {
        const int npair = B * KN;      // 32768 waves, one (b,j) each
        hipLaunchKernelGGL(pgra_gather, dim3((npair + 3) / 4), dim3(256), 0, stream,
                           node, relation, adj_node, adj_rela,
                           node_table, proj_table, costab, agg, npair);
        hipLaunchKernelGGL(pgra_tail4, dim3(B / 4), dim3(256), 0, stream,
                           node, relation, adj_rela, agg,
                           W0, b0, W1, b1, costab, outp);
    } else {
        hipLaunchKernelGGL(pgra_fused, dim3(B), dim3(1024), 0, stream,
                           node, relation, adj_node, adj_rela,
                           node_table, proj_table, W0, b0, W1, b1, costab, outp);
    }
}